// Round 1
// baseline (1023.804 us; speedup 1.0000x reference)
//
#include <hip/hip_runtime.h>

// Adaptive 7x7 max pool over (256,56,56,256) fp32, with the reference's
// transpose(2,1,0,3) index scramble folded into the output index decode.
//
// Output flat index i = ((w*7 + h)*256 + b)*256 + c  ->  pooled[b,h,w,c]
//   c = i & 255, b = (i>>8) & 255, hw = i>>16, h = hw%7, w = hw/7
//
// One thread per output float4 (4 channels). Wave reads 1KB contiguous per
// load (64 lanes x 16B), fully coalesced. 64 loads per thread (8x8 window).

__global__ __launch_bounds__(256)
void roi_max_pool_kernel(const float4* __restrict__ x, float4* __restrict__ out, int n4) {
    int tid4 = blockIdx.x * 256 + threadIdx.x;
    if (tid4 >= n4) return;

    // decode scrambled output position (in float4 units: c4 = c/4, 64 per row)
    int c4 = tid4 & 63;
    int b  = (tid4 >> 6) & 255;
    int hw = tid4 >> 14;          // = w*7 + h
    int h  = hw % 7;
    int w  = hw / 7;

    // input base (float4 units): ((b*56 + h*8)*56 + w*8)*64 + c4
    const float4* __restrict__ p =
        x + ((size_t)((b * 56 + h * 8) * 56 + w * 8) << 6) + c4;

    float4 m = p[0];
    #pragma unroll
    for (int dh = 0; dh < 8; ++dh) {
        #pragma unroll
        for (int dw = 0; dw < 8; ++dw) {
            float4 v = p[(size_t)(dh * 56 + dw) << 6];
            m.x = fmaxf(m.x, v.x);
            m.y = fmaxf(m.y, v.y);
            m.z = fmaxf(m.z, v.z);
            m.w = fmaxf(m.w, v.w);
        }
    }
    out[tid4] = m;
}

extern "C" void kernel_launch(void* const* d_in, const int* in_sizes, int n_in,
                              void* d_out, int out_size, void* d_ws, size_t ws_size,
                              hipStream_t stream) {
    const float4* x = (const float4*)d_in[0];
    float4* out = (float4*)d_out;
    int n4 = out_size / 4;                 // 256*7*7*256/4 = 802816
    int blocks = (n4 + 255) / 256;         // 3136
    roi_max_pool_kernel<<<blocks, 256, 0, stream>>>(x, out, n4);
}